// Round 26
// baseline (503.181 us; speedup 1.0000x reference)
//
#include <hip/hip_runtime.h>

#define N_NODES  500000
#define HIDDEN   256
#define N_GRAPHS 8192
#define NTILES   (N_NODES / 32)          // 15625 tiles of 32 rows (exact)
#define NWIN     (N_NODES / 16)          // 31250 16-row windows
#define PROW     260                     // 256 num + 1 den + pad
#define NB       768                     // grid: 3 blocks/CU (LDS-capped)

typedef float f32x4 __attribute__((ext_vector_type(4)));
typedef short s16x8 __attribute__((ext_vector_type(8)));

typedef __attribute__((address_space(1))) const void gv_t;
typedef __attribute__((address_space(3))) void       lv_t;

__device__ __forceinline__ unsigned short f2bf(float f) {
    unsigned int u = __float_as_uint(f);
    u += 0x7fffu + ((u >> 16) & 1u);   // RNE round to bf16
    return (unsigned short)(u >> 16);
}

__device__ __forceinline__ float bf2f(unsigned short s) {
    return __uint_as_float(((unsigned)s) << 16);
}

// Pack W1 [K=256][N=256] fp32 into bf16 B-fragments (16x16x32 layout).
__global__ void prep_w1_kernel(const float* __restrict__ W1,
                               unsigned short* __restrict__ w1pack) {
    int tid  = blockIdx.x * 256 + threadIdx.x;   // 0..8191
    int lane = tid & 63;
    int slot = tid >> 6;                         // 0..127
    int wv   = slot >> 5;
    int kt   = (slot >> 2) & 7;
    int ntp  = slot & 3;
    int nt   = wv * 4 + ntp;
    int krow = kt * 32 + ((lane >> 4) & 3) * 8;
    int col  = nt * 16 + (lane & 15);
    unsigned short tmp[8];
#pragma unroll
    for (int j = 0; j < 8; ++j)
        tmp[j] = f2bf(W1[(size_t)(krow + j) * 256 + col]);
    *(uint4*)(w1pack + (size_t)tid * 8) = *(const uint4*)tmp;
}

// offsEnd[g] = lower_bound(batch, g+1)
__global__ void offsets_kernel(const int* __restrict__ batch,
                               int* __restrict__ offsEnd) {
    int g = blockIdx.x * 256 + threadIdx.x;
    if (g >= N_GRAPHS) return;
    int lo = 0, hi = N_NODES;
    while (lo < hi) {
        int mid = (lo + hi) >> 1;
        if (batch[mid] < g + 1) lo = mid + 1; else hi = mid;
    }
    offsEnd[g] = lo;
}

// Pipelined fused kernel (round-23 structure) + LDS-walk (round-24 fix).
// Grid-stride over 32-row tiles; async global_load_lds prefetch of tile t+NB
// overlaps GEMM+walk of tile t. Walk reads the resident bf16 bufB (ds_read,
// ~free) instead of global x — removes the 512 MB L2 re-read that doubled
// FETCH and sank round 23. Raw s_barrier + lgkmcnt(0) before the walk keeps
// the prefetch vmcnt in flight; loop-top __syncthreads drains it.
__launch_bounds__(256, 3)
__global__ void fused_kernel(const float* __restrict__ x,
                             const int*   __restrict__ batch,
                             const float* __restrict__ b1,
                             const float* __restrict__ W2,
                             const float* __restrict__ b2,
                             const unsigned short* __restrict__ w1pack,
                             float* __restrict__ preW,
                             float* __restrict__ sufW,
                             float* __restrict__ out) {
    __shared__ float bufA[32 * 256];           // 32 KiB fp32 tile (async dest)
    __shared__ unsigned short bufB[32 * 256];  // 16 KiB bf16, unit-swizzled
    __shared__ float plds[128];                // logit partials [wave][row32]

    const int tid  = threadIdx.x;
    const int wave = tid >> 6;
    const int lane = tid & 63;
    const int cl   = lane & 15;
    const int kgrp = lane >> 4;

    float b1c[4], w2c[4];
#pragma unroll
    for (int ntp = 0; ntp < 4; ++ntp) {
        int nt = wave * 4 + ntp;
        b1c[ntp] = b1[nt * 16 + cl];
        w2c[ntp] = W2[nt * 16 + cl];
    }
    const float b2v = b2[0];

    // ---- prologue: async-stage first tile ----
    {
        int t0 = blockIdx.x;
        if (t0 < NTILES) {
#pragma unroll
            for (int i = 0; i < 8; ++i) {
                int row = wave * 8 + i;
                const float* src = x + (size_t)(t0 * 32 + row) * HIDDEN + lane * 4;
                __builtin_amdgcn_global_load_lds((gv_t*)src,
                                                 (lv_t*)(bufA + row * 256), 16, 0, 0);
            }
        }
    }

    for (int t = blockIdx.x; t < NTILES; t += NB) {
        __syncthreads();   // drains vmcnt: bufA[t] complete+visible; bufB free

        // ---- convert bufA(fp32) -> bufB(bf16, swizzled); each elem once ----
#pragma unroll
        for (int i = 0; i < 4; ++i) {
            int v   = tid + i * 256;      // 0..1023
            int row = v >> 5;
            int cu  = v & 31;
            f32x4 a = *(const f32x4*)(bufA + row * 256 + cu * 8);
            f32x4 c = *(const f32x4*)(bufA + row * 256 + cu * 8 + 4);
            s16x8 w;
            w[0] = (short)f2bf(a[0]); w[1] = (short)f2bf(a[1]);
            w[2] = (short)f2bf(a[2]); w[3] = (short)f2bf(a[3]);
            w[4] = (short)f2bf(c[0]); w[5] = (short)f2bf(c[1]);
            w[6] = (short)f2bf(c[2]); w[7] = (short)f2bf(c[3]);
            *(s16x8*)(bufB + (size_t)(row * 32 + (cu ^ (row & 7))) * 8) = w;
        }
        __syncthreads();   // convert visible; bufA free for next prefetch

        // ---- issue async prefetch of tile t+NB (stays in flight) ----
        if (t + NB < NTILES) {
#pragma unroll
            for (int i = 0; i < 8; ++i) {
                int row = wave * 8 + i;
                const float* src = x + (size_t)((t + NB) * 32 + row) * HIDDEN + lane * 4;
                __builtin_amdgcn_global_load_lds((gv_t*)src,
                                                 (lv_t*)(bufA + row * 256), 16, 0, 0);
            }
        }

        // ---- hoisted walk inputs (overlap GEMM) ----
        const int base = t * 32;
        const int wwin = wave & 1;
        const int ws   = base + wwin * 16;
        int bval  = batch[ws + cl];
        int bprev = (ws > 0) ? batch[ws - 1] : -1;
        int bnext = (ws + 16 < N_NODES) ? batch[ws + 16] : -1;

        // ---- GEMM + tanh: 4 column passes of 16 cols, acc[2] = 8 regs ----
        float sj[2][4];
#pragma unroll
        for (int rt = 0; rt < 2; ++rt)
#pragma unroll
            for (int j = 0; j < 4; ++j) sj[rt][j] = 0.f;

#pragma unroll
        for (int pass = 0; pass < 4; ++pass) {
            f32x4 acc[2];
            acc[0] = (f32x4){0.f, 0.f, 0.f, 0.f};
            acc[1] = (f32x4){0.f, 0.f, 0.f, 0.f};

#pragma unroll
            for (int kt = 0; kt < 8; ++kt) {
                s16x8 bf = *(const s16x8*)(w1pack +
                    ((size_t)(((wave * 8 + kt) * 4 + pass) * 64 + lane) << 3));
#pragma unroll
                for (int rt = 0; rt < 2; ++rt) {
                    int row = rt * 16 + cl;
                    int cu  = kt * 4 + kgrp;
                    s16x8 af = *(const s16x8*)(bufB +
                        (size_t)(row * 32 + (cu ^ (row & 7))) * 8);
                    acc[rt] = __builtin_amdgcn_mfma_f32_16x16x32_bf16(
                        af, bf, acc[rt], 0, 0, 0);
                }
            }
            float bb = b1c[pass];
            float ww = w2c[pass];
#pragma unroll
            for (int rt = 0; rt < 2; ++rt)
#pragma unroll
                for (int j = 0; j < 4; ++j) {
                    float h = acc[rt][j] + bb;
                    h = fminf(fmaxf(h, -15.f), 15.f);
                    float e2 = __expf(2.f * h);
                    float th = (e2 - 1.f) * __builtin_amdgcn_rcpf(e2 + 1.f);
                    sj[rt][j] += th * ww;
                }
        }

#pragma unroll
        for (int m = 1; m < 16; m <<= 1)
#pragma unroll
            for (int rt = 0; rt < 2; ++rt)
#pragma unroll
                for (int j = 0; j < 4; ++j)
                    sj[rt][j] += __shfl_xor(sj[rt][j], m, 64);
        if (cl == 0) {
#pragma unroll
            for (int rt = 0; rt < 2; ++rt)
#pragma unroll
                for (int j = 0; j < 4; ++j)
                    plds[wave * 32 + rt * 16 + kgrp * 4 + j] = sj[rt][j];
        }

        // plds barrier WITHOUT vmcnt drain (keep prefetch in flight)
        asm volatile("s_waitcnt lgkmcnt(0)" ::: "memory");
        __builtin_amdgcn_s_barrier();
        __builtin_amdgcn_sched_barrier(0);

        // ---- waves 0,1: e per row of own 16-row window; walk from bufB ----
        if (wave < 2) {
            const int wid = t * 2 + wave;
            int rr = wwin * 16 + cl;
            float logit = plds[rr] + plds[32 + rr] + plds[64 + rr] + plds[96 + rr] + b2v;
            float el = __expf(logit);

            const int gfirst = __shfl(bval, 0, 64);
            const int glast  = __shfl(bval, 15, 64);
            const bool eb = (bprev == gfirst);
            const bool ef = (bnext == glast);

            // this lane's 4 columns live in half of 16B-unit cu = lane>>1
            const int cuW  = lane >> 1;
            const int half = (lane & 1) * 4;

            f32x4 accv = {0.f, 0.f, 0.f, 0.f};
            float accden = 0.f;
            int gcur = gfirst, sl = 0;
#pragma unroll
            for (int r = 0; r < 16; ++r) {
                int   g  = __shfl(bval, r, 64);
                float er = __shfl(el, r, 64);
                if (g != gcur) {                 // wave-uniform flush (not final)
                    bool sb = (sl == 0) && eb;
                    if (!sb) {                   // fully inside window -> final
                        float d = accden + 1e-8f;
                        f32x4 res;
                        res[0] = accv[0] / d; res[1] = accv[1] / d;
                        res[2] = accv[2] / d; res[3] = accv[3] / d;
                        *(f32x4*)(out + (size_t)gcur * HIDDEN + lane * 4) = res;
                    } else {
                        *(f32x4*)(preW + (size_t)wid * PROW + lane * 4) = accv;
                        if (lane == 0) preW[(size_t)wid * PROW + 256] = accden;
                    }
                    accv = (f32x4){0.f, 0.f, 0.f, 0.f};
                    accden = 0.f;
                    gcur = g; sl = r;
                }
                int rl = wwin * 16 + r;          // row within the 32-row tile
                const unsigned short* u = bufB +
                    (size_t)(rl * 32 + (cuW ^ (rl & 7))) * 8 + half;
                accv[0] += er * bf2f(u[0]);
                accv[1] += er * bf2f(u[1]);
                accv[2] += er * bf2f(u[2]);
                accv[3] += er * bf2f(u[3]);
                accden += er;
            }
            {   // final flush
                bool sb = (sl == 0) && eb;
                if (!sb && !ef) {
                    float d = accden + 1e-8f;
                    f32x4 res;
                    res[0] = accv[0] / d; res[1] = accv[1] / d;
                    res[2] = accv[2] / d; res[3] = accv[3] / d;
                    *(f32x4*)(out + (size_t)gcur * HIDDEN + lane * 4) = res;
                } else if (!sb && sl > 0) {
                    *(f32x4*)(sufW + (size_t)wid * PROW + lane * 4) = accv;
                    if (lane == 0) sufW[(size_t)wid * PROW + 256] = accden;
                } else {
                    *(f32x4*)(preW + (size_t)wid * PROW + lane * 4) = accv;
                    if (lane == 0) preW[(size_t)wid * PROW + 256] = accden;
                }
            }
        }
    }
}

// Combine: one wave per graph; straddlers sum window partials; empty -> zeros.
__launch_bounds__(256)
__global__ void combine_kernel(const float* __restrict__ preW,
                               const float* __restrict__ sufW,
                               const int* __restrict__ offsEnd,
                               float* __restrict__ out) {
    const int g    = blockIdx.x * 4 + (threadIdx.x >> 6);
    const int lane = threadIdx.x & 63;
    if (g >= N_GRAPHS) return;
    const int s = (g == 0) ? 0 : offsEnd[g - 1];
    const int e = offsEnd[g];
    if (e == s) {
        *(f32x4*)(out + (size_t)g * HIDDEN + lane * 4) = (f32x4){0.f, 0.f, 0.f, 0.f};
        return;
    }
    const int w0 = s >> 4, w1 = (e - 1) >> 4;
    if (w0 == w1) return;                        // direct-written

    const float* row = (s > (w0 << 4)) ? sufW + (size_t)w0 * PROW
                                       : preW + (size_t)w0 * PROW;
    f32x4 acc = *(const f32x4*)(row + lane * 4);
    float den = row[256];
    for (int w = w0 + 1; w <= w1; ++w) {
        const float* pr = preW + (size_t)w * PROW;
        acc += *(const f32x4*)(pr + lane * 4);
        den += pr[256];
    }
    float d = den + 1e-8f;
    f32x4 res;
    res[0] = acc[0] / d; res[1] = acc[1] / d;
    res[2] = acc[2] / d; res[3] = acc[3] / d;
    *(f32x4*)(out + (size_t)g * HIDDEN + lane * 4) = res;
}

extern "C" void kernel_launch(void* const* d_in, const int* in_sizes, int n_in,
                              void* d_out, int out_size, void* d_ws, size_t ws_size,
                              hipStream_t stream) {
    const float* x     = (const float*)d_in[0];
    const int*   batch = (const int*)d_in[1];
    const float* W1    = (const float*)d_in[2];
    const float* b1    = (const float*)d_in[3];
    const float* W2    = (const float*)d_in[4];
    const float* b2    = (const float*)d_in[5];
    float* out = (float*)d_out;

    unsigned short* w1pack = (unsigned short*)d_ws;                  // 128 KiB
    int*   offsEnd = (int*)((char*)d_ws + 131072);                   // 32 KiB
    float* preW    = (float*)((char*)d_ws + 163840);                 // 32.5 MB
    float* sufW    = (float*)((char*)d_ws + 163840 + (size_t)NWIN * PROW * 4);

    prep_w1_kernel<<<32, 256, 0, stream>>>(W1, w1pack);
    offsets_kernel<<<32, 256, 0, stream>>>(batch, offsEnd);

    fused_kernel<<<NB, 256, 0, stream>>>(x, batch, b1, W2, b2, w1pack,
                                         preW, sufW, out);
    combine_kernel<<<(N_GRAPHS + 3) / 4, 256, 0, stream>>>(preW, sufW, offsEnd, out);
}

// Round 27
// 197.426 us; speedup vs baseline: 2.5487x; 2.5487x over previous
//
#include <hip/hip_runtime.h>

#define N_NODES  500000
#define HIDDEN   256
#define N_GRAPHS 8192
#define NTILES   (N_NODES / 32)          // 15625 blocks (500000 % 32 == 0)
#define NWIN     (N_NODES / 16)          // 31250 16-row windows
#define PROW     260                     // 256 num + 1 den + pad

typedef float f32x4 __attribute__((ext_vector_type(4)));
typedef short s16x8 __attribute__((ext_vector_type(8)));

__device__ __forceinline__ unsigned short f2bf(float f) {
    unsigned int u = __float_as_uint(f);
    u += 0x7fffu + ((u >> 16) & 1u);   // RNE round to bf16
    return (unsigned short)(u >> 16);
}

__device__ __forceinline__ float bf2f(unsigned short s) {
    return __uint_as_float(((unsigned)s) << 16);
}

// Pack W1 [K=256][N=256] fp32 into bf16 B-fragments (16x16x32 layout).
// slot = (wave*8 + kt)*4 + ntp ; nt = wave*4 + ntp
// w1pack[(slot*64 + lane)*8 + j] = bf16( W1[kt*32 + (lane>>4)*8 + j][nt*16 + (lane&15)] )
__global__ void prep_w1_kernel(const float* __restrict__ W1,
                               unsigned short* __restrict__ w1pack) {
    int tid  = blockIdx.x * 256 + threadIdx.x;   // 0..8191
    int lane = tid & 63;
    int slot = tid >> 6;                         // 0..127
    int wv   = slot >> 5;
    int kt   = (slot >> 2) & 7;
    int ntp  = slot & 3;
    int nt   = wv * 4 + ntp;
    int krow = kt * 32 + ((lane >> 4) & 3) * 8;
    int col  = nt * 16 + (lane & 15);
    unsigned short tmp[8];
#pragma unroll
    for (int j = 0; j < 8; ++j)
        tmp[j] = f2bf(W1[(size_t)(krow + j) * 256 + col]);
    *(uint4*)(w1pack + (size_t)tid * 8) = *(const uint4*)tmp;
}

// offsEnd[g] = lower_bound(batch, g+1)
__global__ void offsets_kernel(const int* __restrict__ batch,
                               int* __restrict__ offsEnd) {
    int g = blockIdx.x * 256 + threadIdx.x;
    if (g >= N_GRAPHS) return;
    int lo = 0, hi = N_NODES;
    while (lo < hi) {
        int mid = (lo + hi) >> 1;
        if (batch[mid] < g + 1) lo = mid + 1; else hi = mid;
    }
    offsEnd[g] = lo;
}

// BEST MEASURED (round 24, 197.6 us): 32-row tiles, 4 waves, bf16-LDS walk.
// Stage fp32->bf16 LDS (swizzled) -> GEMM 4 col-passes acc[2]=8 AGPR ->
// butterfly logit reduce -> plds combine -> waves 0,1 walk own 16-row window
// reading x from the resident bf16 LDS tile (no global re-read).
// Pipelining (r23/r26), occupancy knobs (r20/r25), B-burst (r21), 64-row
// tiles (r22): all measured neutral-or-worse vs this.
__launch_bounds__(256, 3)
__global__ void fused_kernel(const float* __restrict__ x,
                             const int*   __restrict__ batch,
                             const float* __restrict__ b1,
                             const float* __restrict__ W2,
                             const float* __restrict__ b2,
                             const unsigned short* __restrict__ w1pack,
                             float* __restrict__ preW,
                             float* __restrict__ sufW,
                             float* __restrict__ out) {
    __shared__ unsigned short xbf[32 * 256];   // 16 KiB bf16 tile, unit-swizzled
    __shared__ float plds[128];                // logit partials [wave][row32]

    const int tid  = threadIdx.x;
    const int wave = tid >> 6;
    const int lane = tid & 63;
    const int cl   = lane & 15;
    const int kgrp = lane >> 4;
    const int base = blockIdx.x * 32;

    // ---- stage 32-row tile -> bf16 LDS; 16B-unit index ^= (row&7) ----
#pragma unroll
    for (int i = 0; i < 4; ++i) {
        int v   = tid + i * 256;      // 0..1023
        int row = v >> 5;
        int cu  = v & 31;
        const float* p = x + (size_t)(base + row) * HIDDEN + cu * 8;
        f32x4 a = *(const f32x4*)p;
        f32x4 c = *(const f32x4*)(p + 4);
        s16x8 w;
        w[0] = (short)f2bf(a[0]); w[1] = (short)f2bf(a[1]);
        w[2] = (short)f2bf(a[2]); w[3] = (short)f2bf(a[3]);
        w[4] = (short)f2bf(c[0]); w[5] = (short)f2bf(c[1]);
        w[6] = (short)f2bf(c[2]); w[7] = (short)f2bf(c[3]);
        *(s16x8*)(xbf + (size_t)(row * 32 + (cu ^ (row & 7))) * 8) = w;
    }

    // ---- hoisted walk inputs (L2 latency overlaps staging drain) ----
    const int wwin = wave & 1;                // waves 0,1 own windows
    const int wsW  = base + wwin * 16;
    int bval = batch[wsW + cl];
    const int bprev = (wsW > 0) ? batch[wsW - 1] : -1;
    const int bnext = (wsW + 16 < N_NODES) ? batch[wsW + 16] : -1;

    float b1c[4], w2c[4];
#pragma unroll
    for (int ntp = 0; ntp < 4; ++ntp) {
        int nt = wave * 4 + ntp;
        b1c[ntp] = b1[nt * 16 + cl];
        w2c[ntp] = W2[nt * 16 + cl];
    }
    const float b2v = b2[0];
    __syncthreads();

    // ---- GEMM + tanh: 4 column passes of 16 cols, acc[2] = 8 regs ----
    float sj[2][4];
#pragma unroll
    for (int rt = 0; rt < 2; ++rt)
#pragma unroll
        for (int j = 0; j < 4; ++j) sj[rt][j] = 0.f;

#pragma unroll
    for (int pass = 0; pass < 4; ++pass) {
        f32x4 acc[2];
        acc[0] = (f32x4){0.f, 0.f, 0.f, 0.f};
        acc[1] = (f32x4){0.f, 0.f, 0.f, 0.f};

#pragma unroll
        for (int kt = 0; kt < 8; ++kt) {
            s16x8 bf = *(const s16x8*)(w1pack +
                ((size_t)(((wave * 8 + kt) * 4 + pass) * 64 + lane) << 3));
#pragma unroll
            for (int rt = 0; rt < 2; ++rt) {
                int row = rt * 16 + cl;
                int cu  = kt * 4 + kgrp;
                s16x8 af = *(const s16x8*)(xbf +
                    (size_t)(row * 32 + (cu ^ (row & 7))) * 8);
                acc[rt] = __builtin_amdgcn_mfma_f32_16x16x32_bf16(
                    af, bf, acc[rt], 0, 0, 0);
            }
        }
        // tanh + partial logit for these 16 cols
        float bb = b1c[pass];
        float ww = w2c[pass];
#pragma unroll
        for (int rt = 0; rt < 2; ++rt)
#pragma unroll
            for (int j = 0; j < 4; ++j) {
                float h = acc[rt][j] + bb;
                h = fminf(fmaxf(h, -15.f), 15.f);
                float e2 = __expf(2.f * h);
                float th = (e2 - 1.f) * __builtin_amdgcn_rcpf(e2 + 1.f);
                sj[rt][j] += th * ww;
            }
    }

    // reduce across 16 lanes of each kgrp group
#pragma unroll
    for (int m = 1; m < 16; m <<= 1)
#pragma unroll
        for (int rt = 0; rt < 2; ++rt)
#pragma unroll
            for (int j = 0; j < 4; ++j)
                sj[rt][j] += __shfl_xor(sj[rt][j], m, 64);
    if (cl == 0) {
#pragma unroll
        for (int rt = 0; rt < 2; ++rt)
#pragma unroll
            for (int j = 0; j < 4; ++j)
                plds[wave * 32 + rt * 16 + kgrp * 4 + j] = sj[rt][j];
    }
    __syncthreads();

    // ---- waves 0,1: e per row of own 16-row window; walk from bf16 LDS ----
    if (wave < 2) {
        const int wid = blockIdx.x * 2 + wave;
        int rr = wwin * 16 + cl;
        float logit = plds[rr] + plds[32 + rr] + plds[64 + rr] + plds[96 + rr] + b2v;
        float el = __expf(logit);

        const int gfirst = __shfl(bval, 0, 64);
        const int glast  = __shfl(bval, 15, 64);
        const bool eb = (bprev == gfirst);
        const bool ef = (bnext == glast);

        // this lane's 4 columns live in half of 16B-unit cu = lane>>1
        const int cuW  = lane >> 1;
        const int half = (lane & 1) * 4;

        f32x4 accv = {0.f, 0.f, 0.f, 0.f};
        float accden = 0.f;
        int gcur = gfirst, sl = 0;
#pragma unroll
        for (int r = 0; r < 16; ++r) {
            int   g  = __shfl(bval, r, 64);
            float er = __shfl(el, r, 64);
            if (g != gcur) {                     // wave-uniform flush (not final)
                bool sb = (sl == 0) && eb;
                if (!sb) {                       // fully inside window -> final
                    float d = accden + 1e-8f;
                    f32x4 res;
                    res[0] = accv[0] / d; res[1] = accv[1] / d;
                    res[2] = accv[2] / d; res[3] = accv[3] / d;
                    *(f32x4*)(out + (size_t)gcur * HIDDEN + lane * 4) = res;
                } else {
                    *(f32x4*)(preW + (size_t)wid * PROW + lane * 4) = accv;
                    if (lane == 0) preW[(size_t)wid * PROW + 256] = accden;
                }
                accv = (f32x4){0.f, 0.f, 0.f, 0.f};
                accden = 0.f;
                gcur = g; sl = r;
            }
            int rl = wwin * 16 + r;              // row within the 32-row tile
            const unsigned short* u = xbf +
                (size_t)(rl * 32 + (cuW ^ (rl & 7))) * 8 + half;
            accv[0] += er * bf2f(u[0]);
            accv[1] += er * bf2f(u[1]);
            accv[2] += er * bf2f(u[2]);
            accv[3] += er * bf2f(u[3]);
            accden += er;
        }
        {   // final flush
            bool sb = (sl == 0) && eb;
            if (!sb && !ef) {
                float d = accden + 1e-8f;
                f32x4 res;
                res[0] = accv[0] / d; res[1] = accv[1] / d;
                res[2] = accv[2] / d; res[3] = accv[3] / d;
                *(f32x4*)(out + (size_t)gcur * HIDDEN + lane * 4) = res;
            } else if (!sb && sl > 0) {
                *(f32x4*)(sufW + (size_t)wid * PROW + lane * 4) = accv;
                if (lane == 0) sufW[(size_t)wid * PROW + 256] = accden;
            } else {
                *(f32x4*)(preW + (size_t)wid * PROW + lane * 4) = accv;
                if (lane == 0) preW[(size_t)wid * PROW + 256] = accden;
            }
        }
    }
}

// Combine: one wave per graph; straddlers sum window partials; empty -> zeros.
__launch_bounds__(256)
__global__ void combine_kernel(const float* __restrict__ preW,
                               const float* __restrict__ sufW,
                               const int* __restrict__ offsEnd,
                               float* __restrict__ out) {
    const int g    = blockIdx.x * 4 + (threadIdx.x >> 6);
    const int lane = threadIdx.x & 63;
    if (g >= N_GRAPHS) return;
    const int s = (g == 0) ? 0 : offsEnd[g - 1];
    const int e = offsEnd[g];
    if (e == s) {
        *(f32x4*)(out + (size_t)g * HIDDEN + lane * 4) = (f32x4){0.f, 0.f, 0.f, 0.f};
        return;
    }
    const int w0 = s >> 4, w1 = (e - 1) >> 4;
    if (w0 == w1) return;                        // direct-written

    const float* row = (s > (w0 << 4)) ? sufW + (size_t)w0 * PROW
                                       : preW + (size_t)w0 * PROW;
    f32x4 acc = *(const f32x4*)(row + lane * 4);
    float den = row[256];
    for (int w = w0 + 1; w <= w1; ++w) {
        const float* pr = preW + (size_t)w * PROW;
        acc += *(const f32x4*)(pr + lane * 4);
        den += pr[256];
    }
    float d = den + 1e-8f;
    f32x4 res;
    res[0] = acc[0] / d; res[1] = acc[1] / d;
    res[2] = acc[2] / d; res[3] = acc[3] / d;
    *(f32x4*)(out + (size_t)g * HIDDEN + lane * 4) = res;
}

extern "C" void kernel_launch(void* const* d_in, const int* in_sizes, int n_in,
                              void* d_out, int out_size, void* d_ws, size_t ws_size,
                              hipStream_t stream) {
    const float* x     = (const float*)d_in[0];
    const int*   batch = (const int*)d_in[1];
    const float* W1    = (const float*)d_in[2];
    const float* b1    = (const float*)d_in[3];
    const float* W2    = (const float*)d_in[4];
    const float* b2    = (const float*)d_in[5];
    float* out = (float*)d_out;

    unsigned short* w1pack = (unsigned short*)d_ws;                  // 128 KiB
    int*   offsEnd = (int*)((char*)d_ws + 131072);                   // 32 KiB
    float* preW    = (float*)((char*)d_ws + 163840);                 // 32.5 MB
    float* sufW    = (float*)((char*)d_ws + 163840 + (size_t)NWIN * PROW * 4);

    prep_w1_kernel<<<32, 256, 0, stream>>>(W1, w1pack);
    offsets_kernel<<<32, 256, 0, stream>>>(batch, offsEnd);

    fused_kernel<<<NTILES, 256, 0, stream>>>(x, batch, b1, W2, b2, w1pack,
                                             preW, sufW, out);
    combine_kernel<<<(N_GRAPHS + 3) / 4, 256, 0, stream>>>(preW, sufW, offsEnd, out);
}